// Round 3
// baseline (1592.448 us; speedup 1.0000x reference)
//
#include <hip/hip_runtime.h>
#include <math.h>

#define NPTS 4096
#define NBATCH 4
#define BLOCK 256
#define RPW 8                    // rows per wave (register-tiled)
#define NCHUNK 8                 // 8 chunks x (8 cols/lane x 64 lanes) = 4096 cols

static constexpr float KSCALE     = 1.4426950408889634f / 1e-4f;   // log2(e)/eps
static constexpr float INVK2      = 1.0f / (KSCALE * KSCALE);
static constexpr float EPSLN2     = 1e-4f * 0.6931471805599453f;   // eps*ln(2)
static constexpr float NEGEPSLOGW = 8.31776616671934e-4f;          // -eps * (-log(4096))
static constexpr float SKIP_THR   = 26.0f;   // drop chunks with all t < M-26 (mass < 2^-25)

__device__ __forceinline__ float fexp2(float x){
#if __has_builtin(__builtin_amdgcn_exp2f)
  return __builtin_amdgcn_exp2f(x);
#else
  return exp2f(x);
#endif
}
__device__ __forceinline__ float flog2(float x){
#if __has_builtin(__builtin_amdgcn_logf)
  return __builtin_amdgcn_logf(x);
#else
  return log2f(x);
#endif
}

// One launch = two independent softmin problems (512 blocks each).
// Block = 256 thr = 4 independent waves (no barriers, no LDS).
// Wave: 8 rows (coords replicated in all lanes' VGPRs), columns split
// lane-distinct: lane l owns cols {l + 64j}, chunked 8 at a time via
// coalesced float4 loads. Per-lane online LSE per row; chunks whose max
// score is < M-26 for every lane are skipped (wave-uniform vote) -- the
// exp2/rescale block is bypassed, only the 3-FMA dot + max tree run.
// Final: 6-step shfl max, one rescale, 6-step shfl sum per row.
__global__ __launch_bounds__(BLOCK, 4) void softmin_kernel(
    const float* __restrict__ rowA, int rsA, const float4* __restrict__ pkInA,
    float4* __restrict__ pkOutA, const float* __restrict__ hOldA,
    float* __restrict__ outA, int modeA,
    const float* __restrict__ rowB, int rsB, const float4* __restrict__ pkInB,
    float4* __restrict__ pkOutB, const float* __restrict__ hOldB,
    float* __restrict__ outB, int modeB)
{
  int bid = blockIdx.x;
  const float* rowp; const float4* pkin; float4* pkout; const float* hold;
  float* outp; int rs, mode;
  if (bid < 512) { rowp=rowA; pkin=pkInA; pkout=pkOutA; hold=hOldA; outp=outA; rs=rsA; mode=modeA; }
  else           { rowp=rowB; pkin=pkInB; pkout=pkOutB; hold=hOldB; outp=outB; rs=rsB; mode=modeB; }
  int lb = bid & 511;
  int b  = lb >> 7;          // batch
  int rb = lb & 127;         // row-block (32 rows per block)

  int tid = threadIdx.x;
  int w = tid >> 6, lane = tid & 63;
  int r0 = rb*32 + w*RPW;
  int ridx0 = b*NPTS + r0;

  // row coords, premultiplied by KSCALE, replicated across lanes
  float ptx[RPW], pty[RPW], ptz[RPW];
  #pragma unroll
  for (int i = 0; i < RPW; ++i) {
    const float* p = rowp + (size_t)(ridx0 + i) * rs;
    ptx[i] = p[0]*KSCALE; pty[i] = p[1]*KSCALE; ptz[i] = p[2]*KSCALE;
  }

  float M[RPW], S[RPW];
  #pragma unroll
  for (int i = 0; i < RPW; ++i) { M[i] = -INFINITY; S[i] = 0.f; }

  const float4* pk = pkin + b*NPTS + lane;

  for (int c = 0; c < NCHUNK; ++c) {
    const float4* pc = pk + c*512;
    float4 q0 = pc[0],   q1 = pc[64],  q2 = pc[128], q3 = pc[192];
    float4 q4 = pc[256], q5 = pc[320], q6 = pc[384], q7 = pc[448];
    #pragma unroll
    for (int r = 0; r < RPW; ++r) {
      float ax = ptx[r], ay = pty[r], az = ptz[r];
      float t0 = fmaf(ax, q0.x, fmaf(ay, q0.y, fmaf(az, q0.z, q0.w)));
      float t1 = fmaf(ax, q1.x, fmaf(ay, q1.y, fmaf(az, q1.z, q1.w)));
      float t2 = fmaf(ax, q2.x, fmaf(ay, q2.y, fmaf(az, q2.z, q2.w)));
      float t3 = fmaf(ax, q3.x, fmaf(ay, q3.y, fmaf(az, q3.z, q3.w)));
      float t4 = fmaf(ax, q4.x, fmaf(ay, q4.y, fmaf(az, q4.z, q4.w)));
      float t5 = fmaf(ax, q5.x, fmaf(ay, q5.y, fmaf(az, q5.z, q5.w)));
      float t6 = fmaf(ax, q6.x, fmaf(ay, q6.y, fmaf(az, q6.z, q6.w)));
      float t7 = fmaf(ax, q7.x, fmaf(ay, q7.y, fmaf(az, q7.z, q7.w)));
      float cmax = fmaxf(fmaxf(fmaxf(t0,t1), fmaxf(t2,t3)),
                         fmaxf(fmaxf(t4,t5), fmaxf(t6,t7)));
      if (__any(cmax > M[r] - SKIP_THR)) {
        float Mn = fmaxf(M[r], cmax);
        float sc = fexp2(M[r] - Mn);
        float e0 = fexp2(t0-Mn) + fexp2(t1-Mn);
        float e1 = fexp2(t2-Mn) + fexp2(t3-Mn);
        float e2 = fexp2(t4-Mn) + fexp2(t5-Mn);
        float e3 = fexp2(t6-Mn) + fexp2(t7-Mn);
        S[r] = fmaf(S[r], sc, (e0+e1) + (e2+e3));
        M[r] = Mn;
      }
    }
  }

  // cross-lane merge per row: global max -> single rescale -> sum
  #pragma unroll
  for (int r = 0; r < RPW; ++r) {
    float m = M[r];
    #pragma unroll
    for (int off = 32; off > 0; off >>= 1) m = fmaxf(m, __shfl_xor(m, off, 64));
    float s = S[r] * fexp2(M[r] - m);
    #pragma unroll
    for (int off = 32; off > 0; off >>= 1) s += __shfl_xor(s, off, 64);
    float ch = 0.5f*(ptx[r]*ptx[r] + pty[r]*pty[r] + ptz[r]*ptz[r]) * INVK2;
    float res = fmaf(-EPSLN2, m + flog2(s), ch + NEGEPSLOGW);
    if (lane == r) {
      if (mode) res = 0.5f*(hold[ridx0 + r] + res);
      outp[ridx0 + r] = res;
      ((float*)(pkout + (ridx0 + r)))[3] = (res - ch) * KSCALE;
    }
  }
}

// Build the 6 packed column arrays once per launch. .w gets the h=0 initial Atilde.
__global__ void pack_init(const float* __restrict__ x, const float* __restrict__ y,
                          float4* pkfab, float4* pkgab,
                          float4* pkfaa0, float4* pkfaa1,
                          float4* pkgbb0, float4* pkgbb1)
{
  int i = blockIdx.x*256 + threadIdx.x;        // 0..16383 == b*4096+m
  const float* xp = x + (size_t)i*3;
  float xx = xp[0], xy = xp[1], xz = xp[2];
  float4 vx; vx.x=xx; vx.y=xy; vx.z=xz;
  vx.w = -0.5f*(xx*xx + xy*xy + xz*xz)*KSCALE;
  const float* yp = y + (size_t)i*4;
  float yx = yp[0], yy = yp[1], yz = yp[2];
  float4 vy; vy.x=yx; vy.y=yy; vy.z=yz;
  vy.w = -0.5f*(yx*yx + yy*yy + yz*yz)*KSCALE;
  pkgab[i]  = vx; pkfaa0[i] = vx; pkfaa1[i] = vx;
  pkfab[i]  = vy; pkgbb0[i] = vy; pkgbb1[i] = vy;
}

__global__ void reduce_kernel(const float* __restrict__ fab, const float* __restrict__ faa,
                              const float* __restrict__ gab, const float* __restrict__ gbb,
                              float* __restrict__ out)
{
  int b = blockIdx.x;
  int tid = threadIdx.x;
  float s = 0.f;
  for (int i = tid; i < NPTS; i += 256) {
    int idx = b*NPTS + i;
    s += (fab[idx] - faa[idx]) + (gab[idx] - gbb[idx]);
  }
  for (int off = 32; off > 0; off >>= 1) s += __shfl_down(s, off, 64);
  __shared__ float red[4];
  if ((tid & 63) == 0) red[tid >> 6] = s;
  __syncthreads();
  if (tid == 0) out[b] = (red[0]+red[1]+red[2]+red[3]) * (1.0f/NPTS);
}

extern "C" void kernel_launch(void* const* d_in, const int* in_sizes, int n_in,
                              void* d_out, int out_size, void* d_ws, size_t ws_size,
                              hipStream_t stream)
{
  const float* x = (const float*)d_in[0];   // (4,4096,3)
  const float* y = (const float*)d_in[1];   // (4,4096,4), first 3 comps used
  float* ws = (float*)d_ws;
  const size_t P = (size_t)NBATCH * NPTS;   // 16384

  float* f_ab    = ws + 0*P;
  float* g_ab    = ws + 1*P;
  float* faaR[2] = { ws + 2*P, ws + 4*P };
  float* gbbR[2] = { ws + 3*P, ws + 5*P };
  float4* pk4    = (float4*)(ws + 6*P);
  float4* PKfab    = pk4 + 0*P;             // cols = y, .w = Atilde(g_ab)
  float4* PKgab    = pk4 + 1*P;             // cols = x, .w = Atilde(f_ab)
  float4* PKfaa[2] = { pk4 + 2*P, pk4 + 3*P };
  float4* PKgbb[2] = { pk4 + 4*P, pk4 + 5*P };

  // zero h_old for the first averaged symmetric step (faaR[0], gbbR[0] contiguous)
  hipMemsetAsync(ws + 2*P, 0, 2*P*sizeof(float), stream);
  pack_init<<<dim3(P/256), dim3(256), 0, stream>>>(x, y, PKfab, PKgab,
                                                   PKfaa[0], PKfaa[1], PKgbb[0], PKgbb[1]);

  for (int i = 0; i < 21; ++i) {
    int cur = i & 1, nxt = cur ^ 1;
    int modeS = (i < 20) ? 1 : 0;    // averaged symmetric update except final softmin
    // phase 1: f_ab = softmin over y-cols (Atilde from g_ab)  ||  f_aa step
    softmin_kernel<<<1024, BLOCK, 0, stream>>>(
        x, 3, PKfab, PKgab, f_ab, f_ab, 0,
        x, 3, PKfaa[cur], PKfaa[nxt], faaR[cur], faaR[nxt], modeS);
    // phase 2: g_ab = softmin over x-cols (Atilde from f_ab)  ||  g_bb step
    softmin_kernel<<<1024, BLOCK, 0, stream>>>(
        y, 4, PKgab, PKfab, g_ab, g_ab, 0,
        y, 4, PKgbb[cur], PKgbb[nxt], gbbR[cur], gbbR[nxt], modeS);
  }
  // i=20 wrote faaR[1]/gbbR[1]
  reduce_kernel<<<dim3(4), dim3(256), 0, stream>>>(f_ab, faaR[1], g_ab, gbbR[1], (float*)d_out);
}